// Round 1
// baseline (269.767 us; speedup 1.0000x reference)
//
#include <hip/hip_runtime.h>
#include <math.h>

constexpr int kB = 256;      // batches
constexpr int kT = 261;      // tokens per batch
constexpr int kD = 768;      // dim
constexpr int kC = 5;        // cue tokens (1 + NUM_REG)
constexpr int kG = 16;       // patch grid
constexpr int kP = 256;      // patches per batch
constexpr int kThreads = 768;
constexpr int kD4 = kD / 4;

__global__ __launch_bounds__(kThreads, 1)
void mve_kernel(const float* __restrict__ tokens,
                const float* __restrict__ W,      // (D,D): W[j*kD + d], t[j] = sum_d x[d]*W[j,d]
                const float* __restrict__ bias,
                float* __restrict__ out)          // (B, 10, D)
{
    __shared__ alignas(16) float bufA[kC * kD];   // cues -> u -> roi means
    __shared__ alignas(16) float tcb[kC * kD];    // t_c + b
    __shared__ alignas(16) float red3[3 * kP * kC]; // sim partials (3 d-segments)
    __shared__ double argv[kP];
    __shared__ int    argi[kP];
    __shared__ int    bestn[kC];
    __shared__ float  normred[12 * 10];
    __shared__ float  norml[10];

    const int b = blockIdx.x;
    const int t = threadIdx.x;
    const size_t tokbase = (size_t)b * kT * kD;

    // ---- Phase 0: load the 5 cue rows (first 5*768 floats of this batch) ----
    for (int i = t; i < kC * kD; i += kThreads)
        bufA[i] = tokens[tokbase + i];
    __syncthreads();

    // ---- Phase 1: tcb[c][j] = sum_d cue[c][d] * W[j][d] + b[j]  (fp64 acc), j = t ----
    {
        const int j = t;
        double acc[kC] = {0.0, 0.0, 0.0, 0.0, 0.0};
        const float4* W4 = reinterpret_cast<const float4*>(W + (size_t)j * kD);
        const float4* c4 = reinterpret_cast<const float4*>(bufA);
        for (int d4 = 0; d4 < kD4; ++d4) {
            float4 w = W4[d4];
            #pragma unroll
            for (int c = 0; c < kC; ++c) {
                float4 v = c4[c * kD4 + d4];
                acc[c] += (double)w.x * v.x + (double)w.y * v.y
                        + (double)w.z * v.z + (double)w.w * v.w;
            }
        }
        float bj = bias[j];
        #pragma unroll
        for (int c = 0; c < kC; ++c)
            tcb[c * kD + j] = (float)acc[c] + bj;
    }
    __syncthreads();

    // ---- Phase 2: u[c][i] = sum_j tcb[c][j] * W[j][i]  (fp64 acc), i = t; overwrite bufA ----
    {
        const int i = t;
        double acc[kC] = {0.0, 0.0, 0.0, 0.0, 0.0};
        #pragma unroll 4
        for (int j = 0; j < kD; ++j) {
            float w = W[(size_t)j * kD + i];       // coalesced across lanes
            #pragma unroll
            for (int c = 0; c < kC; ++c)
                acc[c] += (double)w * (double)tcb[c * kD + j];  // LDS broadcast
        }
        #pragma unroll
        for (int c = 0; c < kC; ++c)
            bufA[c * kD + i] = (float)acc[c];
    }
    __syncthreads();

    // ---- Phase 3: sims. sim[c][n] = u[c] . patch[n]; d split into 3 segments of 256 ----
    {
        const int n   = t & (kP - 1);
        const int seg = t >> 8;
        const float4* p4 = reinterpret_cast<const float4*>(
            tokens + tokbase + (size_t)(kC + n) * kD + (size_t)seg * 256);
        const float4* u4 = reinterpret_cast<const float4*>(bufA + seg * 256);
        double acc[kC] = {0.0, 0.0, 0.0, 0.0, 0.0};
        for (int d4 = 0; d4 < 64; ++d4) {
            float4 p = p4[d4];
            #pragma unroll
            for (int c = 0; c < kC; ++c) {
                float4 u = u4[c * kD4 + d4];       // uniform within wave -> broadcast
                acc[c] += (double)p.x * u.x + (double)p.y * u.y
                        + (double)p.z * u.z + (double)p.w * u.w;
            }
        }
        #pragma unroll
        for (int c = 0; c < kC; ++c)
            red3[(seg * kP + n) * kC + c] = (float)acc[c];
    }
    __syncthreads();

    // ---- Phase 3b: per-cue argmax over 256 patches (first-index tie-break) ----
    {
        double s[kC];
        if (t < kP) {
            #pragma unroll
            for (int c = 0; c < kC; ++c)
                s[c] = (double)red3[(0 * kP + t) * kC + c]
                     + (double)red3[(1 * kP + t) * kC + c]
                     + (double)red3[(2 * kP + t) * kC + c];
        }
        for (int c = 0; c < kC; ++c) {
            if (t < kP) { argv[t] = s[c]; argi[t] = t; }
            __syncthreads();
            for (int off = kP / 2; off >= 1; off >>= 1) {
                if (t < off) {
                    double v2 = argv[t + off]; int i2 = argi[t + off];
                    if (v2 > argv[t] || (v2 == argv[t] && i2 < argi[t])) {
                        argv[t] = v2; argi[t] = i2;
                    }
                }
                __syncthreads();
            }
            if (t == 0) bestn[c] = argi[0];
            __syncthreads();
        }
    }

    // ---- Phase 4: raw ROI means into bufA (d = t) ----
    {
        const int d = t;
        #pragma unroll
        for (int c = 0; c < kC; ++c) {
            int n = bestn[c];
            int h = n >> 4, w = n & (kG - 1);
            int rlo = max(h - 1, 0), rhi = min(h + 1, kG - 1);
            int clo = max(w - 1, 0), chi = min(w + 1, kG - 1);
            float sum = 0.0f;
            for (int rr = rlo; rr <= rhi; ++rr)
                for (int cc = clo; cc <= chi; ++cc)
                    sum += tokens[tokbase + (size_t)(kC + rr * kG + cc) * kD + d];
            float cnt = (float)((rhi - rlo + 1) * (chi - clo + 1));
            bufA[c * kD + d] = sum / cnt;
        }
    }
    __syncthreads();

    // ---- Phase 5: project ROI means (+bias), gather cue vals, normalize, write ----
    {
        const int j = t;
        float racc[kC] = {0.f, 0.f, 0.f, 0.f, 0.f};
        const float4* W4 = reinterpret_cast<const float4*>(W + (size_t)j * kD);
        const float4* r4 = reinterpret_cast<const float4*>(bufA);
        for (int d4 = 0; d4 < kD4; ++d4) {
            float4 w = W4[d4];
            #pragma unroll
            for (int c = 0; c < kC; ++c) {
                float4 v = r4[c * kD4 + d4];
                racc[c] += w.x * v.x + w.y * v.y + w.z * v.z + w.w * v.w;
            }
        }
        float bj = bias[j];
        float vals[10];
        #pragma unroll
        for (int c = 0; c < kC; ++c) vals[c] = tcb[c * kD + j];
        #pragma unroll
        for (int c = 0; c < kC; ++c) vals[kC + c] = racc[c] + bj;

        const int lane = t & 63, wid = t >> 6;
        #pragma unroll
        for (int k = 0; k < 10; ++k) {
            float sq = vals[k] * vals[k];
            #pragma unroll
            for (int off = 32; off >= 1; off >>= 1)
                sq += __shfl_down(sq, off, 64);
            if (lane == 0) normred[wid * 10 + k] = sq;
        }
        __syncthreads();
        if (t < 10) {
            float ssum = 0.0f;
            for (int w2 = 0; w2 < 12; ++w2) ssum += normred[w2 * 10 + t];
            norml[t] = fmaxf(sqrtf(ssum), 1e-12f);
        }
        __syncthreads();
        const size_t ob = (size_t)b * 10 * kD;
        #pragma unroll
        for (int k = 0; k < 10; ++k)
            out[ob + (size_t)k * kD + j] = vals[k] / norml[k];
    }
}

extern "C" void kernel_launch(void* const* d_in, const int* in_sizes, int n_in,
                              void* d_out, int out_size, void* d_ws, size_t ws_size,
                              hipStream_t stream) {
    const float* tokens = (const float*)d_in[0];
    const float* W      = (const float*)d_in[1];
    const float* bias   = (const float*)d_in[2];
    float* out = (float*)d_out;
    mve_kernel<<<dim3(kB), dim3(kThreads), 0, stream>>>(tokens, W, bias, out);
}

// Round 2
// 267.185 us; speedup vs baseline: 1.0097x; 1.0097x over previous
//
#include <hip/hip_runtime.h>
#include <math.h>

constexpr int kB = 256;      // batches
constexpr int kT = 261;      // tokens per batch
constexpr int kD = 768;      // dim
constexpr int kC = 5;        // cue tokens (1 + NUM_REG)
constexpr int kG = 16;       // patch grid
constexpr int kP = 256;      // patches per batch
constexpr int kThreads = 768;
constexpr int kD4 = kD / 4;

__global__ __launch_bounds__(kThreads, 1)
void mve_kernel(const float* __restrict__ tokens,
                const float* __restrict__ W,      // (D,D) row-major: t[j] = sum_d x[d]*W[j*kD+d]
                const float* __restrict__ bias,
                float* __restrict__ out)          // (B, 10, D)
{
    // fp64 ping-pong buffers: d64a = cues_d -> u_d ; d64b = tcb_d -> sim partials
    __shared__ alignas(16) double d64a[kC * kD];          // 30 KB
    __shared__ alignas(16) double d64b[kC * kD];          // 30 KB (= 3*256*5 doubles for partials)
    __shared__ alignas(16) float  tcb_f[kC * kD];         // 15 KB
    __shared__ alignas(16) float  roi_f[kC * kD];         // 15 KB
    __shared__ int    bestn[kC];
    __shared__ float  normred[12 * 10];
    __shared__ float  norml[10];

    const int b = blockIdx.x;
    const int t = threadIdx.x;
    const size_t tokbase = (size_t)b * kT * kD;

    // ---- Phase 0: load cue rows, convert to fp64 LDS once ----
    #pragma unroll
    for (int k = 0; k < kC; ++k) {
        int i = t + k * kThreads;                 // kC*kD == 5*kThreads exactly
        d64a[i] = (double)tokens[tokbase + i];
    }
    __syncthreads();

    // ---- Phase 1: tcb[c][j] = sum_d cue_d[c][d] * W[j][d] + b[j]  (fp64 acc), j = t ----
    {
        const int j = t;
        double acc[kC] = {0.0, 0.0, 0.0, 0.0, 0.0};
        const float4* W4 = reinterpret_cast<const float4*>(W + (size_t)j * kD);
        for (int d4 = 0; d4 < kD4; ++d4) {
            float4 w = W4[d4];
            const double wx = (double)w.x, wy = (double)w.y;
            const double wz = (double)w.z, ww = (double)w.w;
            #pragma unroll
            for (int c = 0; c < kC; ++c) {
                const double* cu = &d64a[c * kD + d4 * 4];   // broadcast reads
                acc[c] += wx * cu[0] + wy * cu[1] + wz * cu[2] + ww * cu[3];
            }
        }
        const double bj = (double)bias[j];
        #pragma unroll
        for (int c = 0; c < kC; ++c) {
            double v = acc[c] + bj;
            tcb_f[c * kD + j] = (float)v;
            d64b[c * kD + j]  = v;
        }
    }
    __syncthreads();

    // ---- Phase 2: u[c][i] = sum_j tcb_d[c][j] * W[j][i]  (fp64 acc), i = t ----
    {
        const int i = t;
        double acc[kC] = {0.0, 0.0, 0.0, 0.0, 0.0};
        #pragma unroll 4
        for (int j = 0; j < kD; ++j) {
            const double w = (double)W[(size_t)j * kD + i];  // coalesced across lanes
            #pragma unroll
            for (int c = 0; c < kC; ++c)
                acc[c] += w * d64b[c * kD + j];              // LDS broadcast, no cvt
        }
        __syncthreads();   // all phase-2 reads of d64b done before phase-3 overwrites it;
                           // (phase-1 reads of d64a ended at the previous barrier)
        #pragma unroll
        for (int c = 0; c < kC; ++c)
            d64a[c * kD + i] = acc[c];                       // u_d overwrites cues_d
    }
    __syncthreads();

    // ---- Phase 3: sims fp64. sim[c][n] = u_d[c] . patch[n]; d split into 3 segs of 256 ----
    {
        const int n   = t & (kP - 1);
        const int seg = t >> 8;
        const float4* p4 = reinterpret_cast<const float4*>(
            tokens + tokbase + (size_t)(kC + n) * kD + (size_t)seg * 256);
        double acc[kC] = {0.0, 0.0, 0.0, 0.0, 0.0};
        for (int d4 = 0; d4 < 64; ++d4) {
            float4 p = p4[d4];
            const double px = (double)p.x, py = (double)p.y;
            const double pz = (double)p.z, pw = (double)p.w;
            #pragma unroll
            for (int c = 0; c < kC; ++c) {
                const double* u = &d64a[c * kD + seg * 256 + d4 * 4];  // broadcast
                acc[c] += px * u[0] + py * u[1] + pz * u[2] + pw * u[3];
            }
        }
        #pragma unroll
        for (int c = 0; c < kC; ++c)
            d64b[(seg * kP + n) * kC + c] = acc[c];          // partials (3*256*5 doubles)
    }
    __syncthreads();

    // ---- Phase 3b: per-cue argmax via one wave per cue (no barriers, fp64 compare) ----
    {
        const int wid = t >> 6, lane = t & 63;
        if (wid < kC) {
            const int c = wid;
            double best = -1.0e300; int bi = 0;
            #pragma unroll
            for (int k = 0; k < 4; ++k) {
                int n = lane + k * 64;                       // ascending n per lane
                double v = d64b[(0 * kP + n) * kC + c]
                         + d64b[(1 * kP + n) * kC + c]
                         + d64b[(2 * kP + n) * kC + c];      // same seg order as before
                if (v > best || (v == best && n < bi)) { best = v; bi = n; }
            }
            #pragma unroll
            for (int off = 32; off >= 1; off >>= 1) {
                double v2 = __shfl_down(best, off, 64);
                int    i2 = __shfl_down(bi,   off, 64);
                if (v2 > best || (v2 == best && i2 < bi)) { best = v2; bi = i2; }
            }
            if (lane == 0) bestn[c] = bi;
        }
    }
    __syncthreads();

    // ---- Phase 4: raw ROI means (fp32), d = t ----
    {
        const int d = t;
        #pragma unroll
        for (int c = 0; c < kC; ++c) {
            int n = bestn[c];
            int h = n >> 4, w = n & (kG - 1);
            int rlo = max(h - 1, 0), rhi = min(h + 1, kG - 1);
            int clo = max(w - 1, 0), chi = min(w + 1, kG - 1);
            float sum = 0.0f;
            for (int rr = rlo; rr <= rhi; ++rr)
                for (int cc = clo; cc <= chi; ++cc)
                    sum += tokens[tokbase + (size_t)(kC + rr * kG + cc) * kD + d];
            float cnt = (float)((rhi - rlo + 1) * (chi - clo + 1));
            roi_f[c * kD + d] = sum / cnt;
        }
    }
    __syncthreads();

    // ---- Phase 5: project ROI means (+bias), gather cue vals, normalize, write ----
    {
        const int j = t;
        float racc[kC] = {0.f, 0.f, 0.f, 0.f, 0.f};
        const float4* W4 = reinterpret_cast<const float4*>(W + (size_t)j * kD);
        const float4* r4 = reinterpret_cast<const float4*>(roi_f);
        for (int d4 = 0; d4 < kD4; ++d4) {
            float4 w = W4[d4];
            #pragma unroll
            for (int c = 0; c < kC; ++c) {
                float4 v = r4[c * kD4 + d4];
                racc[c] += w.x * v.x + w.y * v.y + w.z * v.z + w.w * v.w;
            }
        }
        float bj = bias[j];
        float vals[10];
        #pragma unroll
        for (int c = 0; c < kC; ++c) vals[c] = tcb_f[c * kD + j];
        #pragma unroll
        for (int c = 0; c < kC; ++c) vals[kC + c] = racc[c] + bj;

        const int lane = t & 63, wid = t >> 6;
        #pragma unroll
        for (int k = 0; k < 10; ++k) {
            float sq = vals[k] * vals[k];
            #pragma unroll
            for (int off = 32; off >= 1; off >>= 1)
                sq += __shfl_down(sq, off, 64);
            if (lane == 0) normred[wid * 10 + k] = sq;
        }
        __syncthreads();
        if (t < 10) {
            float ssum = 0.0f;
            for (int w2 = 0; w2 < 12; ++w2) ssum += normred[w2 * 10 + t];
            norml[t] = fmaxf(sqrtf(ssum), 1e-12f);
        }
        __syncthreads();
        const size_t ob = (size_t)b * 10 * kD;
        #pragma unroll
        for (int k = 0; k < 10; ++k)
            out[ob + (size_t)k * kD + j] = vals[k] / norml[k];
    }
}

extern "C" void kernel_launch(void* const* d_in, const int* in_sizes, int n_in,
                              void* d_out, int out_size, void* d_ws, size_t ws_size,
                              hipStream_t stream) {
    const float* tokens = (const float*)d_in[0];
    const float* W      = (const float*)d_in[1];
    const float* bias   = (const float*)d_in[2];
    float* out = (float*)d_out;
    mve_kernel<<<dim3(kB), dim3(kThreads), 0, stream>>>(tokens, W, bias, out);
}